// Round 14
// baseline (175.849 us; speedup 1.0000x reference)
//
#include <hip/hip_runtime.h>
#include <stdint.h>

#define S_LEN 1024
#define DDIM  512
#define NBATCH 16

typedef __attribute__((ext_vector_type(8))) short bf16x8;
typedef __attribute__((ext_vector_type(4))) float f32x4;
typedef unsigned short ushort_t;

__device__ __forceinline__ unsigned short f2bf(float x) {
  union { float f; uint32_t u; } v; v.f = x;
  return (unsigned short)((v.u + 0x7fffu + ((v.u >> 16) & 1u)) >> 16);
}
__device__ __forceinline__ float bf2f(unsigned short h) {
  union { float f; uint32_t u; } v; v.u = ((uint32_t)h) << 16;
  return v.f;
}

// offset arg stays 0 — K-advance via compile-time pointer math (R7 lesson).
#define GL16(g, l) __builtin_amdgcn_global_load_lds(                          \
    (const __attribute__((address_space(1))) void*)(g),                       \
    (__attribute__((address_space(3))) void*)(l), 16, 0, 0)

// ---------------------------------------------------------------------------
// K1: per-row prep: sj[row] = P[row,:]·wb ; Pbf = bf16(P) ; Qbf = bf16(P*wc)
__global__ __launch_bounds__(256) void prep_rows(
    const float* __restrict__ P, const float* __restrict__ w_atten,
    unsigned short* __restrict__ Pbf, unsigned short* __restrict__ Qbf,
    float* __restrict__ sj) {
  int wave = threadIdx.x >> 6, lane = threadIdx.x & 63;
  int row = blockIdx.x * 4 + wave;
  const float* prow = P + (size_t)row * DDIM;
  float s = 0.f;
#pragma unroll
  for (int h = 0; h < 2; ++h) {
    int d = h * 256 + lane * 4;
    float4 p  = *(const float4*)(prow + d);
    float4 wb = *(const float4*)(w_atten + DDIM + d);
    float4 wc = *(const float4*)(w_atten + 2 * DDIM + d);
    s += p.x * wb.x + p.y * wb.y + p.z * wb.z + p.w * wb.w;
    ushort4 pb, qb;
    pb.x = f2bf(p.x); pb.y = f2bf(p.y); pb.z = f2bf(p.z); pb.w = f2bf(p.w);
    qb.x = f2bf(p.x * wc.x); qb.y = f2bf(p.y * wc.y);
    qb.z = f2bf(p.z * wc.z); qb.w = f2bf(p.w * wc.w);
    *(ushort4*)(Pbf + (size_t)row * DDIM + d) = pb;
    *(ushort4*)(Qbf + (size_t)row * DDIM + d) = qb;
  }
#pragma unroll
  for (int o = 32; o; o >>= 1) s += __shfl_xor(s, o);
  if (lane == 0) sj[row] = s;
}

// ---------------------------------------------------------------------------
// K2: bf16 transpose (reads Pbf) — Pbf[R][C] -> PT[C][R] per batch
__global__ __launch_bounds__(256) void transpose_b2b(
    const unsigned short* __restrict__ in, unsigned short* __restrict__ out,
    int R, int C, long inStride, long outStride) {
  __shared__ unsigned short T[64][65];
  in  += (size_t)blockIdx.z * inStride;
  out += (size_t)blockIdx.z * outStride;
  int c0 = blockIdx.x * 64, r0 = blockIdx.y * 64;
  int tx = threadIdx.x & 63, ty = threadIdx.x >> 6;
#pragma unroll
  for (int rr = 0; rr < 16; ++rr) {
    int rl = ty * 16 + rr;
    T[rl][tx] = in[(size_t)(r0 + rl) * C + c0 + tx];
  }
  __syncthreads();
#pragma unroll
  for (int rr = 0; rr < 16; ++rr) {
    int cl = ty * 16 + rr;
    out[(size_t)(c0 + cl) * R + r0 + tx] = T[tx][cl];
  }
}

// ---------------------------------------------------------------------------
// transpose_w3: the 3 weight transposes in ONE dispatch (z selects source).
__global__ __launch_bounds__(256) void transpose_w3(
    const float* __restrict__ w1, const float* __restrict__ w2,
    const float* __restrict__ w3, unsigned short* __restrict__ out) {
  __shared__ unsigned short T[64][65];
  const float* in = (blockIdx.z == 0) ? w1 : ((blockIdx.z == 1) ? w2 : w3);
  out += (size_t)blockIdx.z * (DDIM * S_LEN);
  int c0 = blockIdx.x * 64, r0 = blockIdx.y * 64;
  int tx = threadIdx.x & 63, ty = threadIdx.x >> 6;
#pragma unroll
  for (int rr = 0; rr < 16; ++rr) {
    int rl = ty * 16 + rr;
    T[rl][tx] = f2bf(in[(size_t)(r0 + rl) * 512 + c0 + tx]);
  }
  __syncthreads();
#pragma unroll
  for (int rr = 0; rr < 16; ++rr) {
    int cl = ty * 16 + rr;
    out[(size_t)(c0 + cl) * 1024 + r0 + tx] = T[tx][cl];
  }
}

// ---------------------------------------------------------------------------
// Triple-buffered 128x128 bf16 NT GEMM (R8/R9-proven) — scores.
#define GSTEP(KT)                                                             \
  if constexpr ((KT) < NT) {                                                  \
    if constexpr ((KT) + 2 < NT) {                                            \
      ushort_t* dA_ = lA[((KT) + 2) % 3];                                     \
      ushort_t* dB_ = lB[((KT) + 2) % 3];                                     \
      GL16(aLo0 + ((KT) + 2) * 32, dA_ + lbase);                              \
      GL16(aLo1 + ((KT) + 2) * 32, dA_ + 2048 + lbase);                       \
      GL16(bB0 + ((KT) + 2) * 32, dB_ + lbase);                               \
      GL16(bB1 + ((KT) + 2) * 32, dB_ + 2048 + lbase);                        \
    }                                                                         \
    {                                                                         \
      const ushort_t* Ard_ = lA[(KT) % 3];                                    \
      const ushort_t* Brd_ = lB[(KT) % 3];                                    \
      bf16x8 af[4], bfr[4];                                                   \
      _Pragma("unroll") for (int m = 0; m < 4; ++m)                           \
        af[m] = *(const bf16x8*)(Ard_ + (wr * 64 + m * 16 + frow) * 32 + fswz); \
      _Pragma("unroll") for (int n = 0; n < 4; ++n)                           \
        bfr[n] = *(const bf16x8*)(Brd_ + (wc * 64 + n * 16 + frow) * 32 + fswz); \
      __builtin_amdgcn_s_setprio(1);                                          \
      _Pragma("unroll") for (int m = 0; m < 4; ++m)                           \
      _Pragma("unroll") for (int n = 0; n < 4; ++n)                           \
        acc[m][n] = __builtin_amdgcn_mfma_f32_16x16x32_bf16(af[m], bfr[n],    \
                                                            acc[m][n], 0, 0, 0); \
      __builtin_amdgcn_s_setprio(0);                                          \
    }                                                                         \
    if constexpr ((KT) + 1 < NT) {                                            \
      if constexpr ((KT) + 2 < NT)                                            \
        asm volatile("s_waitcnt vmcnt(4) lgkmcnt(0)" ::: "memory");           \
      else                                                                    \
        asm volatile("s_waitcnt vmcnt(0) lgkmcnt(0)" ::: "memory");           \
      __builtin_amdgcn_s_barrier();                                           \
    }                                                                         \
  }

template<int NT, int EPI>
__global__ __launch_bounds__(256) void gemm_tb(
    const ushort_t* __restrict__ A,
    const ushort_t* __restrict__ Bt,
    ushort_t* __restrict__ C,
    const float* __restrict__ bias,
    int N, int K, int lda,
    long sAb, long sBb, long sCb, long sBiasb) {
  __shared__ __align__(16) ushort_t lA[3][4096];
  __shared__ __align__(16) ushort_t lB[3][4096];
  const int t = threadIdx.x, lane = t & 63, wave = t >> 6;

  const int gx = gridDim.x, gy = gridDim.y;
  int hblk = blockIdx.x + gx * (blockIdx.y + gy * blockIdx.z);
  int cpx = (gx * gy * (int)gridDim.z) >> 3;
  int wk = (hblk & 7) * cpx + (hblk >> 3);
  const int bx = wk % gx; int rem = wk / gx;
  const int by = rem % gy;
  const int z  = rem / gy;

  A += (size_t)z * sAb;
  Bt += (size_t)z * sBb;
  C += (size_t)z * sCb;
  if (bias) bias += (size_t)z * sBiasb;
  const int bm = by * 128, bn = bx * 128;

  f32x4 acc[4][4];
#pragma unroll
  for (int m = 0; m < 4; ++m)
#pragma unroll
    for (int n = 0; n < 4; ++n) acc[m][n] = {0.f, 0.f, 0.f, 0.f};

  const int wr = wave >> 1, wc = wave & 1;
  const int frow = lane & 15;
  const int fswz = (((lane >> 4) ^ ((frow >> 1) & 3)) * 8);
  const int srow = t >> 2;
  const int skc = (((t & 3) ^ ((t >> 3) & 3)) * 8);
  const int lbase = (t & 192) * 8;

  const ushort_t* aLo0 = A + (size_t)(bm + srow) * lda + skc;
  const ushort_t* aLo1 = aLo0 + (size_t)64 * lda;
  const ushort_t* bB0  = Bt + (size_t)(bn + srow) * K + skc;
  const ushort_t* bB1  = bB0 + (size_t)64 * K;

  GL16(aLo0,      lA[0] + lbase);   GL16(aLo1,      lA[0] + 2048 + lbase);
  GL16(bB0,       lB[0] + lbase);   GL16(bB1,       lB[0] + 2048 + lbase);
  GL16(aLo0 + 32, lA[1] + lbase);   GL16(aLo1 + 32, lA[1] + 2048 + lbase);
  GL16(bB0 + 32,  lB[1] + lbase);   GL16(bB1 + 32,  lB[1] + 2048 + lbase);
  asm volatile("s_waitcnt vmcnt(4)" ::: "memory");
  __builtin_amdgcn_s_barrier();

  GSTEP(0)  GSTEP(1)  GSTEP(2)  GSTEP(3)  GSTEP(4)  GSTEP(5)  GSTEP(6)  GSTEP(7)
  GSTEP(8)  GSTEP(9)  GSTEP(10) GSTEP(11) GSTEP(12) GSTEP(13) GSTEP(14) GSTEP(15)
  GSTEP(16) GSTEP(17) GSTEP(18) GSTEP(19) GSTEP(20) GSTEP(21) GSTEP(22) GSTEP(23)
  GSTEP(24) GSTEP(25) GSTEP(26) GSTEP(27) GSTEP(28) GSTEP(29) GSTEP(30) GSTEP(31)

#pragma unroll
  for (int m = 0; m < 4; ++m) {
    int row0 = bm + wr * 64 + m * 16 + (lane >> 4) * 4;
#pragma unroll
    for (int n = 0; n < 4; ++n) {
      int col = bn + wc * 64 + n * 16 + frow;
      float bc = (EPI >= 1) ? bias[col] : 0.f;
#pragma unroll
      for (int i = 0; i < 4; ++i) {
        float v = acc[m][n][i];
        if (EPI == 1) v += bc;
        C[(size_t)(row0 + i) * N + col] = f2bf(v);
      }
    }
  }
}

// ---------------------------------------------------------------------------
// gemm_64: triple-buffered 128x64 NT GEMM (R10-verified code) — PV only.
// 36 KB LDS -> 4 blocks/CU; counted vmcnt(3).
#define G64STEP(KT)                                                           \
  if constexpr ((KT) < NT) {                                                  \
    if constexpr ((KT) + 2 < NT) {                                            \
      ushort_t* dA_ = lA[((KT) + 2) % 3];                                     \
      ushort_t* dB_ = lB[((KT) + 2) % 3];                                     \
      GL16(aLo0 + ((KT) + 2) * 32, dA_ + lbase);                              \
      GL16(aLo1 + ((KT) + 2) * 32, dA_ + 2048 + lbase);                       \
      GL16(bB0 + ((KT) + 2) * 32, dB_ + lbase);                               \
    }                                                                         \
    {                                                                         \
      const ushort_t* Ard_ = lA[(KT) % 3];                                    \
      const ushort_t* Brd_ = lB[(KT) % 3];                                    \
      bf16x8 af[4], bfr[2];                                                   \
      _Pragma("unroll") for (int m = 0; m < 4; ++m)                           \
        af[m] = *(const bf16x8*)(Ard_ + (wr * 64 + m * 16 + frow) * 32 + fswz); \
      _Pragma("unroll") for (int n = 0; n < 2; ++n)                           \
        bfr[n] = *(const bf16x8*)(Brd_ + (wc * 32 + n * 16 + frow) * 32 + fswz); \
      __builtin_amdgcn_s_setprio(1);                                          \
      _Pragma("unroll") for (int m = 0; m < 4; ++m)                           \
      _Pragma("unroll") for (int n = 0; n < 2; ++n)                           \
        acc[m][n] = __builtin_amdgcn_mfma_f32_16x16x32_bf16(af[m], bfr[n],    \
                                                            acc[m][n], 0, 0, 0); \
      __builtin_amdgcn_s_setprio(0);                                          \
    }                                                                         \
    if constexpr ((KT) + 1 < NT) {                                            \
      if constexpr ((KT) + 2 < NT)                                            \
        asm volatile("s_waitcnt vmcnt(3) lgkmcnt(0)" ::: "memory");           \
      else                                                                    \
        asm volatile("s_waitcnt vmcnt(0) lgkmcnt(0)" ::: "memory");           \
      __builtin_amdgcn_s_barrier();                                           \
    }                                                                         \
  }

template<int NT>
__global__ __launch_bounds__(256) void gemm_64(
    const ushort_t* __restrict__ A,
    const ushort_t* __restrict__ Bt,
    ushort_t* __restrict__ C,
    int N, int K, int lda,
    long sAb, long sBb, long sCb) {
  __shared__ __align__(16) ushort_t lA[3][4096];
  __shared__ __align__(16) ushort_t lB[3][2048];
  const int t = threadIdx.x, lane = t & 63, wave = t >> 6;

  const int gx = gridDim.x, gy = gridDim.y;
  int hblk = blockIdx.x + gx * (blockIdx.y + gy * blockIdx.z);
  int cpx = (gx * gy * (int)gridDim.z) >> 3;
  int wk = (hblk & 7) * cpx + (hblk >> 3);
  const int bx = wk % gx; int rem = wk / gx;
  const int by = rem % gy;
  const int z  = rem / gy;

  A += (size_t)z * sAb;
  Bt += (size_t)z * sBb;
  C += (size_t)z * sCb;
  const int bm = by * 128, bn = bx * 64;

  f32x4 acc[4][2];
#pragma unroll
  for (int m = 0; m < 4; ++m)
#pragma unroll
    for (int n = 0; n < 2; ++n) acc[m][n] = {0.f, 0.f, 0.f, 0.f};

  const int wr = wave >> 1, wc = wave & 1;
  const int frow = lane & 15;
  const int fswz = (((lane >> 4) ^ ((frow >> 1) & 3)) * 8);
  const int srow = t >> 2;
  const int skc = (((t & 3) ^ ((t >> 3) & 3)) * 8);
  const int lbase = (t & 192) * 8;

  const ushort_t* aLo0 = A + (size_t)(bm + srow) * lda + skc;
  const ushort_t* aLo1 = aLo0 + (size_t)64 * lda;
  const ushort_t* bB0  = Bt + (size_t)(bn + srow) * K + skc;

  GL16(aLo0,      lA[0] + lbase);  GL16(aLo1,      lA[0] + 2048 + lbase);
  GL16(bB0,       lB[0] + lbase);
  GL16(aLo0 + 32, lA[1] + lbase);  GL16(aLo1 + 32, lA[1] + 2048 + lbase);
  GL16(bB0 + 32,  lB[1] + lbase);
  asm volatile("s_waitcnt vmcnt(3)" ::: "memory");
  __builtin_amdgcn_s_barrier();

  G64STEP(0)  G64STEP(1)  G64STEP(2)  G64STEP(3)  G64STEP(4)  G64STEP(5)
  G64STEP(6)  G64STEP(7)  G64STEP(8)  G64STEP(9)  G64STEP(10) G64STEP(11)
  G64STEP(12) G64STEP(13) G64STEP(14) G64STEP(15) G64STEP(16) G64STEP(17)
  G64STEP(18) G64STEP(19) G64STEP(20) G64STEP(21) G64STEP(22) G64STEP(23)
  G64STEP(24) G64STEP(25) G64STEP(26) G64STEP(27) G64STEP(28) G64STEP(29)
  G64STEP(30) G64STEP(31)

#pragma unroll
  for (int m = 0; m < 4; ++m) {
    int row0 = bm + wr * 64 + m * 16 + (lane >> 4) * 4;
#pragma unroll
    for (int n = 0; n < 2; ++n) {
      int col = bn + wc * 32 + n * 16 + frow;
#pragma unroll
      for (int i = 0; i < 4; ++i)
        C[(size_t)(row0 + i) * N + col] = f2bf(acc[m][n][i]);
    }
  }
}

// ---------------------------------------------------------------------------
// Fused MLP (R10-exact: triple-buffered A+B, counted vmcnt(5)).
#define MSTEP(KT)                                                             \
  {                                                                           \
    if constexpr ((KT) + 2 < 32) {                                            \
      ushort_t* dA_ = lA[((KT) + 2) % 3];                                     \
      ushort_t* dB_ = lB[((KT) + 2) % 3];                                     \
      if constexpr ((KT) + 2 < 16) {                                          \
        GL16(aLo0 + ((KT) + 2) * 32, dA_ + lbase);                            \
        GL16(aLo1 + ((KT) + 2) * 32, dA_ + 2048 + lbase);                     \
      } else {                                                                \
        GL16(aHi0 + ((KT) + 2 - 16) * 32, dA_ + lbase);                       \
        GL16(aHi1 + ((KT) + 2 - 16) * 32, dA_ + 2048 + lbase);                \
      }                                                                       \
      GL16(bS0 + ((KT) + 2) * 32, dB_ + lbase);                               \
      GL16(bS1 + ((KT) + 2) * 32, dB_ + 2048 + lbase);                        \
      GL16(bS2 + ((KT) + 2) * 32, dB_ + 4096 + lbase);                        \
    }                                                                         \
    {                                                                         \
      const ushort_t* Ard_ = lA[(KT) % 3];                                    \
      const ushort_t* Brd_ = lB[(KT) % 3];                                    \
      bf16x8 af[4];                                                           \
      _Pragma("unroll") for (int m = 0; m < 4; ++m)                           \
        af[m] = *(const bf16x8*)(Ard_ + (wr * 64 + m * 16 + frow) * 32 + fswz); \
      _Pragma("unroll") for (int s = 0; s < 3; ++s) {                         \
        bf16x8 b0 = *(const bf16x8*)(Brd_ + s * 2048 +                        \
                                     (wc * 32 + frow) * 32 + fswz);           \
        bf16x8 b1v = *(const bf16x8*)(Brd_ + s * 2048 +                       \
                                      (wc * 32 + 16 + frow) * 32 + fswz);     \
        __builtin_amdgcn_s_setprio(1);                                        \
        _Pragma("unroll") for (int m = 0; m < 4; ++m) {                       \
          acc[s][m][0] = __builtin_amdgcn_mfma_f32_16x16x32_bf16(             \
              af[m], b0, acc[s][m][0], 0, 0, 0);                              \
          acc[s][m][1] = __builtin_amdgcn_mfma_f32_16x16x32_bf16(             \
              af[m], b1v, acc[s][m][1], 0, 0, 0);                             \
        }                                                                     \
        __builtin_amdgcn_s_setprio(0);                                        \
      }                                                                       \
    }                                                                         \
    if constexpr ((KT) + 1 < 32) {                                            \
      if constexpr ((KT) + 2 < 32)                                            \
        asm volatile("s_waitcnt vmcnt(5) lgkmcnt(0)" ::: "memory");           \
      else                                                                    \
        asm volatile("s_waitcnt vmcnt(0) lgkmcnt(0)" ::: "memory");           \
      __builtin_amdgcn_s_barrier();                                           \
    }                                                                         \
  }

__global__ __launch_bounds__(256, 2) void mlp_fused(
    const ushort_t* __restrict__ Pbf,
    const ushort_t* __restrict__ attn,
    const ushort_t* __restrict__ Wt,
    const float* __restrict__ P,
    const float* __restrict__ b1,
    const float* __restrict__ b2,
    const float* __restrict__ b3,
    float* __restrict__ out) {
  __shared__ __align__(16) ushort_t lA[3][4096];
  __shared__ __align__(16) ushort_t lB[3][3 * 2048];
  const int t = threadIdx.x, lane = t & 63, wave = t >> 6;

  int hblk = blockIdx.x + 8 * blockIdx.y;
  int wk = (hblk & 7) * 128 + (hblk >> 3);
  const int bx = wk & 7;
  const int by = wk >> 3;
  const int bm = by * 128, bn = bx * 64;

  f32x4 acc[3][4][2];
#pragma unroll
  for (int s = 0; s < 3; ++s)
#pragma unroll
    for (int m = 0; m < 4; ++m)
#pragma unroll
      for (int n = 0; n < 2; ++n) acc[s][m][n] = {0.f, 0.f, 0.f, 0.f};

  const int wr = wave >> 1, wc = wave & 1;
  const int frow = lane & 15;
  const int fswz = (((lane >> 4) ^ ((frow >> 1) & 3)) * 8);
  const int srow = t >> 2;
  const int skc = (((t & 3) ^ ((t >> 3) & 3)) * 8);
  const int lbase = (t & 192) * 8;

  const ushort_t* aLo0 = Pbf + (size_t)(bm + srow) * 512 + skc;
  const ushort_t* aLo1 = aLo0 + (size_t)64 * 512;
  const ushort_t* aHi0 = attn + (size_t)(bm + srow) * 512 + skc;
  const ushort_t* aHi1 = aHi0 + (size_t)64 * 512;
  const ushort_t* bS0 = Wt + (size_t)(bn + srow) * 1024 + skc;
  const ushort_t* bS1 = bS0 + (size_t)512 * 1024;
  const ushort_t* bS2 = bS0 + (size_t)1024 * 1024;

  GL16(aLo0,      lA[0] + lbase);  GL16(aLo1,      lA[0] + 2048 + lbase);
  GL16(bS0,       lB[0] + lbase);  GL16(bS1,       lB[0] + 2048 + lbase);
  GL16(bS2,       lB[0] + 4096 + lbase);
  GL16(aLo0 + 32, lA[1] + lbase);  GL16(aLo1 + 32, lA[1] + 2048 + lbase);
  GL16(bS0 + 32,  lB[1] + lbase);  GL16(bS1 + 32,  lB[1] + 2048 + lbase);
  GL16(bS2 + 32,  lB[1] + 4096 + lbase);
  asm volatile("s_waitcnt vmcnt(5)" ::: "memory");
  __builtin_amdgcn_s_barrier();

  MSTEP(0)  MSTEP(1)  MSTEP(2)  MSTEP(3)  MSTEP(4)  MSTEP(5)  MSTEP(6)  MSTEP(7)
  MSTEP(8)  MSTEP(9)  MSTEP(10) MSTEP(11) MSTEP(12) MSTEP(13) MSTEP(14) MSTEP(15)
  MSTEP(16) MSTEP(17) MSTEP(18) MSTEP(19) MSTEP(20) MSTEP(21) MSTEP(22) MSTEP(23)
  MSTEP(24) MSTEP(25) MSTEP(26) MSTEP(27) MSTEP(28) MSTEP(29) MSTEP(30) MSTEP(31)

#pragma unroll
  for (int m = 0; m < 4; ++m) {
    int row0 = bm + wr * 64 + m * 16 + (lane >> 4) * 4;
#pragma unroll
    for (int n = 0; n < 2; ++n) {
      int col = bn + wc * 32 + n * 16 + frow;
      float B1 = b1[col], B2 = b2[col], B3 = b3[col];
#pragma unroll
      for (int i = 0; i < 4; ++i) {
        size_t idx = (size_t)(row0 + i) * 512 + col;
        float z = tanhf(acc[0][m][n][i] + B1);
        float r = 1.f / (1.f + __expf(-(acc[1][m][n][i] + B2)));
        float f = 1.f / (1.f + __expf(-(acc[2][m][n][i] + B3)));
        out[idx] = r * P[idx] + f * z;
      }
    }
  }
}

// ---------------------------------------------------------------------------
// softmax: in-place row softmax over 1024 bf16 scores, one block per row
__global__ __launch_bounds__(256) void softmax_rows(unsigned short* __restrict__ Sb) {
  __shared__ float red[8];
  unsigned short* p = Sb + (size_t)blockIdx.x * S_LEN;
  int t = threadIdx.x, wave = t >> 6, lane = t & 63;
  ushort4 u = *(ushort4*)(p + t * 4);
  float v0 = bf2f(u.x), v1 = bf2f(u.y), v2 = bf2f(u.z), v3 = bf2f(u.w);
  float mx = fmaxf(fmaxf(v0, v1), fmaxf(v2, v3));
#pragma unroll
  for (int o = 32; o; o >>= 1) mx = fmaxf(mx, __shfl_xor(mx, o));
  if (lane == 0) red[wave] = mx;
  __syncthreads();
  mx = fmaxf(fmaxf(red[0], red[1]), fmaxf(red[2], red[3]));
  float e0 = __expf(v0 - mx), e1 = __expf(v1 - mx);
  float e2 = __expf(v2 - mx), e3 = __expf(v3 - mx);
  float ss = e0 + e1 + e2 + e3;
#pragma unroll
  for (int o = 32; o; o >>= 1) ss += __shfl_xor(ss, o);
  if (lane == 0) red[4 + wave] = ss;
  __syncthreads();
  float inv = 1.f / (red[4] + red[5] + red[6] + red[7]);
  u.x = f2bf(e0 * inv); u.y = f2bf(e1 * inv);
  u.z = f2bf(e2 * inv); u.w = f2bf(e3 * inv);
  *(ushort4*)(p + t * 4) = u;
}

// ---------------------------------------------------------------------------
extern "C" void kernel_launch(void* const* d_in, const int* in_sizes, int n_in,
                              void* d_out, int out_size, void* d_ws, size_t ws_size,
                              hipStream_t stream) {
  const float* P  = (const float*)d_in[0];
  const float* wa = (const float*)d_in[1];
  const float* w1 = (const float*)d_in[2];
  const float* w2 = (const float*)d_in[3];
  const float* w3 = (const float*)d_in[4];
  const float* b1 = (const float*)d_in[5];
  const float* b2 = (const float*)d_in[6];
  const float* b3 = (const float*)d_in[7];
  float* out = (float*)d_out;
  char* ws = (char*)d_ws;
  const size_t MB = 1024 * 1024;

  unsigned short* Pbf  = (unsigned short*)(ws + 0);        // 16 MB
  unsigned short* PT   = (unsigned short*)(ws + 16 * MB);  // 16 MB
  unsigned short* Qbf  = (unsigned short*)(ws + 32 * MB);  // 16 MB
  unsigned short* Sbuf = (unsigned short*)(ws + 48 * MB);  // 32 MB
  unsigned short* attn = (unsigned short*)(ws + 80 * MB);  // 16 MB
  unsigned short* Wt   = (unsigned short*)(ws + 96 * MB);  // 3 MB [1536][1024]
  float*          sj   = (float*)(ws + 99 * MB);           // 64 KB

  const long SD = (long)S_LEN * DDIM;
  const long SS = (long)S_LEN * S_LEN;

  prep_rows<<<4096, 256, 0, stream>>>(P, wa, Pbf, Qbf, sj);
  transpose_b2b<<<dim3(8, 16, NBATCH), 256, 0, stream>>>(Pbf, PT, S_LEN, DDIM, SD, SD);
  transpose_w3<<<dim3(8, 16, 3), 256, 0, stream>>>(w1, w2, w3, Wt);

  // scores: S[b] = Qbf[b] @ Pbf[b]^T + sj[b][col]  (M=N=1024, K=512) — 1024 blocks
  gemm_tb<16, 1><<<dim3(8, 8, NBATCH), 256, 0, stream>>>(
      Qbf, Pbf, Sbuf, sj, 1024, 512, 512, SD, SD, SS, S_LEN);
  softmax_rows<<<16384, 256, 0, stream>>>(Sbuf);
  // attn[b] = SA[b] @ PT[b]^T  (M=1024, N=512, K=1024) — 1024 blocks, 4/CU
  gemm_64<32><<<dim3(8, 8, NBATCH), 256, 0, stream>>>(
      Sbuf, PT, attn, 512, 1024, 1024, SS, SD, SD);
  // fused MLP + gate combine
  mlp_fused<<<dim3(8, 128), 256, 0, stream>>>(
      Pbf, attn, Wt, P, b1, b2, b3, out);
}

// Round 15
// 173.359 us; speedup vs baseline: 1.0144x; 1.0144x over previous
//
#include <hip/hip_runtime.h>
#include <stdint.h>

#define S_LEN 1024
#define DDIM  512
#define NBATCH 16

typedef __attribute__((ext_vector_type(8))) short bf16x8;
typedef __attribute__((ext_vector_type(4))) float f32x4;
typedef unsigned short ushort_t;

__device__ __forceinline__ unsigned short f2bf(float x) {
  union { float f; uint32_t u; } v; v.f = x;
  return (unsigned short)((v.u + 0x7fffu + ((v.u >> 16) & 1u)) >> 16);
}
__device__ __forceinline__ float bf2f(unsigned short h) {
  union { float f; uint32_t u; } v; v.u = ((uint32_t)h) << 16;
  return v.f;
}

// offset arg stays 0 — K-advance via compile-time pointer math (R7 lesson).
#define GL16(g, l) __builtin_amdgcn_global_load_lds(                          \
    (const __attribute__((address_space(1))) void*)(g),                       \
    (__attribute__((address_space(3))) void*)(l), 16, 0, 0)

// ---------------------------------------------------------------------------
// K1: per-row prep: sj[row] = P[row,:]·wb ; Pbf = bf16(P) ; Qbf = bf16(P*wc)
__global__ __launch_bounds__(256) void prep_rows(
    const float* __restrict__ P, const float* __restrict__ w_atten,
    unsigned short* __restrict__ Pbf, unsigned short* __restrict__ Qbf,
    float* __restrict__ sj) {
  int wave = threadIdx.x >> 6, lane = threadIdx.x & 63;
  int row = blockIdx.x * 4 + wave;
  const float* prow = P + (size_t)row * DDIM;
  float s = 0.f;
#pragma unroll
  for (int h = 0; h < 2; ++h) {
    int d = h * 256 + lane * 4;
    float4 p  = *(const float4*)(prow + d);
    float4 wb = *(const float4*)(w_atten + DDIM + d);
    float4 wc = *(const float4*)(w_atten + 2 * DDIM + d);
    s += p.x * wb.x + p.y * wb.y + p.z * wb.z + p.w * wb.w;
    ushort4 pb, qb;
    pb.x = f2bf(p.x); pb.y = f2bf(p.y); pb.z = f2bf(p.z); pb.w = f2bf(p.w);
    qb.x = f2bf(p.x * wc.x); qb.y = f2bf(p.y * wc.y);
    qb.z = f2bf(p.z * wc.z); qb.w = f2bf(p.w * wc.w);
    *(ushort4*)(Pbf + (size_t)row * DDIM + d) = pb;
    *(ushort4*)(Qbf + (size_t)row * DDIM + d) = qb;
  }
#pragma unroll
  for (int o = 32; o; o >>= 1) s += __shfl_xor(s, o);
  if (lane == 0) sj[row] = s;
}

// ---------------------------------------------------------------------------
// K2: bf16 transpose (reads Pbf) — Pbf[R][C] -> PT[C][R] per batch
__global__ __launch_bounds__(256) void transpose_b2b(
    const unsigned short* __restrict__ in, unsigned short* __restrict__ out,
    int R, int C, long inStride, long outStride) {
  __shared__ unsigned short T[64][65];
  in  += (size_t)blockIdx.z * inStride;
  out += (size_t)blockIdx.z * outStride;
  int c0 = blockIdx.x * 64, r0 = blockIdx.y * 64;
  int tx = threadIdx.x & 63, ty = threadIdx.x >> 6;
#pragma unroll
  for (int rr = 0; rr < 16; ++rr) {
    int rl = ty * 16 + rr;
    T[rl][tx] = in[(size_t)(r0 + rl) * C + c0 + tx];
  }
  __syncthreads();
#pragma unroll
  for (int rr = 0; rr < 16; ++rr) {
    int cl = ty * 16 + rr;
    out[(size_t)(c0 + cl) * R + r0 + tx] = T[tx][cl];
  }
}

// ---------------------------------------------------------------------------
// transpose_w3: the 3 weight transposes in ONE dispatch (z selects source).
__global__ __launch_bounds__(256) void transpose_w3(
    const float* __restrict__ w1, const float* __restrict__ w2,
    const float* __restrict__ w3, unsigned short* __restrict__ out) {
  __shared__ unsigned short T[64][65];
  const float* in = (blockIdx.z == 0) ? w1 : ((blockIdx.z == 1) ? w2 : w3);
  out += (size_t)blockIdx.z * (DDIM * S_LEN);
  int c0 = blockIdx.x * 64, r0 = blockIdx.y * 64;
  int tx = threadIdx.x & 63, ty = threadIdx.x >> 6;
#pragma unroll
  for (int rr = 0; rr < 16; ++rr) {
    int rl = ty * 16 + rr;
    T[rl][tx] = f2bf(in[(size_t)(r0 + rl) * 512 + c0 + tx]);
  }
  __syncthreads();
#pragma unroll
  for (int rr = 0; rr < 16; ++rr) {
    int cl = ty * 16 + rr;
    out[(size_t)(c0 + cl) * 1024 + r0 + tx] = T[tx][cl];
  }
}

// ---------------------------------------------------------------------------
// Triple-buffered 128x128 bf16 NT GEMM (R8/R9-proven) — scores & PV.
// EPI: 0 plain; 1 +bias[col].
#define GSTEP(KT)                                                             \
  if constexpr ((KT) < NT) {                                                  \
    if constexpr ((KT) + 2 < NT) {                                            \
      ushort_t* dA_ = lA[((KT) + 2) % 3];                                     \
      ushort_t* dB_ = lB[((KT) + 2) % 3];                                     \
      GL16(aLo0 + ((KT) + 2) * 32, dA_ + lbase);                              \
      GL16(aLo1 + ((KT) + 2) * 32, dA_ + 2048 + lbase);                       \
      GL16(bB0 + ((KT) + 2) * 32, dB_ + lbase);                               \
      GL16(bB1 + ((KT) + 2) * 32, dB_ + 2048 + lbase);                        \
    }                                                                         \
    {                                                                         \
      const ushort_t* Ard_ = lA[(KT) % 3];                                    \
      const ushort_t* Brd_ = lB[(KT) % 3];                                    \
      bf16x8 af[4], bfr[4];                                                   \
      _Pragma("unroll") for (int m = 0; m < 4; ++m)                           \
        af[m] = *(const bf16x8*)(Ard_ + (wr * 64 + m * 16 + frow) * 32 + fswz); \
      _Pragma("unroll") for (int n = 0; n < 4; ++n)                           \
        bfr[n] = *(const bf16x8*)(Brd_ + (wc * 64 + n * 16 + frow) * 32 + fswz); \
      __builtin_amdgcn_s_setprio(1);                                          \
      _Pragma("unroll") for (int m = 0; m < 4; ++m)                           \
      _Pragma("unroll") for (int n = 0; n < 4; ++n)                           \
        acc[m][n] = __builtin_amdgcn_mfma_f32_16x16x32_bf16(af[m], bfr[n],    \
                                                            acc[m][n], 0, 0, 0); \
      __builtin_amdgcn_s_setprio(0);                                          \
    }                                                                         \
    if constexpr ((KT) + 1 < NT) {                                            \
      if constexpr ((KT) + 2 < NT)                                            \
        asm volatile("s_waitcnt vmcnt(4) lgkmcnt(0)" ::: "memory");           \
      else                                                                    \
        asm volatile("s_waitcnt vmcnt(0) lgkmcnt(0)" ::: "memory");           \
      __builtin_amdgcn_s_barrier();                                           \
    }                                                                         \
  }

template<int NT, int EPI>
__global__ __launch_bounds__(256) void gemm_tb(
    const ushort_t* __restrict__ A,
    const ushort_t* __restrict__ Bt,
    ushort_t* __restrict__ C,
    const float* __restrict__ bias,
    int N, int K, int lda,
    long sAb, long sBb, long sCb, long sBiasb) {
  __shared__ __align__(16) ushort_t lA[3][4096];
  __shared__ __align__(16) ushort_t lB[3][4096];
  const int t = threadIdx.x, lane = t & 63, wave = t >> 6;

  const int gx = gridDim.x, gy = gridDim.y;
  int hblk = blockIdx.x + gx * (blockIdx.y + gy * blockIdx.z);
  int cpx = (gx * gy * (int)gridDim.z) >> 3;
  int wk = (hblk & 7) * cpx + (hblk >> 3);
  const int bx = wk % gx; int rem = wk / gx;
  const int by = rem % gy;
  const int z  = rem / gy;

  A += (size_t)z * sAb;
  Bt += (size_t)z * sBb;
  C += (size_t)z * sCb;
  if (bias) bias += (size_t)z * sBiasb;
  const int bm = by * 128, bn = bx * 128;

  f32x4 acc[4][4];
#pragma unroll
  for (int m = 0; m < 4; ++m)
#pragma unroll
    for (int n = 0; n < 4; ++n) acc[m][n] = {0.f, 0.f, 0.f, 0.f};

  const int wr = wave >> 1, wc = wave & 1;
  const int frow = lane & 15;
  const int fswz = (((lane >> 4) ^ ((frow >> 1) & 3)) * 8);
  const int srow = t >> 2;
  const int skc = (((t & 3) ^ ((t >> 3) & 3)) * 8);
  const int lbase = (t & 192) * 8;

  const ushort_t* aLo0 = A + (size_t)(bm + srow) * lda + skc;
  const ushort_t* aLo1 = aLo0 + (size_t)64 * lda;
  const ushort_t* bB0  = Bt + (size_t)(bn + srow) * K + skc;
  const ushort_t* bB1  = bB0 + (size_t)64 * K;

  GL16(aLo0,      lA[0] + lbase);   GL16(aLo1,      lA[0] + 2048 + lbase);
  GL16(bB0,       lB[0] + lbase);   GL16(bB1,       lB[0] + 2048 + lbase);
  GL16(aLo0 + 32, lA[1] + lbase);   GL16(aLo1 + 32, lA[1] + 2048 + lbase);
  GL16(bB0 + 32,  lB[1] + lbase);   GL16(bB1 + 32,  lB[1] + 2048 + lbase);
  asm volatile("s_waitcnt vmcnt(4)" ::: "memory");
  __builtin_amdgcn_s_barrier();

  GSTEP(0)  GSTEP(1)  GSTEP(2)  GSTEP(3)  GSTEP(4)  GSTEP(5)  GSTEP(6)  GSTEP(7)
  GSTEP(8)  GSTEP(9)  GSTEP(10) GSTEP(11) GSTEP(12) GSTEP(13) GSTEP(14) GSTEP(15)
  GSTEP(16) GSTEP(17) GSTEP(18) GSTEP(19) GSTEP(20) GSTEP(21) GSTEP(22) GSTEP(23)
  GSTEP(24) GSTEP(25) GSTEP(26) GSTEP(27) GSTEP(28) GSTEP(29) GSTEP(30) GSTEP(31)

#pragma unroll
  for (int m = 0; m < 4; ++m) {
    int row0 = bm + wr * 64 + m * 16 + (lane >> 4) * 4;
#pragma unroll
    for (int n = 0; n < 4; ++n) {
      int col = bn + wc * 64 + n * 16 + frow;
      float bc = (EPI >= 1) ? bias[col] : 0.f;
#pragma unroll
      for (int i = 0; i < 4; ++i) {
        float v = acc[m][n][i];
        if (EPI == 1) v += bc;
        C[(size_t)(row0 + i) * N + col] = f2bf(v);
      }
    }
  }
}

// ---------------------------------------------------------------------------
// Fused MLP (R10-exact: triple-buffered A+B, counted vmcnt(5)).
// One block computes z,r,f for a 128x64 out-tile; out = r*P + f*z (fp32).
#define MSTEP(KT)                                                             \
  {                                                                           \
    if constexpr ((KT) + 2 < 32) {                                            \
      ushort_t* dA_ = lA[((KT) + 2) % 3];                                     \
      ushort_t* dB_ = lB[((KT) + 2) % 3];                                     \
      if constexpr ((KT) + 2 < 16) {                                          \
        GL16(aLo0 + ((KT) + 2) * 32, dA_ + lbase);                            \
        GL16(aLo1 + ((KT) + 2) * 32, dA_ + 2048 + lbase);                     \
      } else {                                                                \
        GL16(aHi0 + ((KT) + 2 - 16) * 32, dA_ + lbase);                       \
        GL16(aHi1 + ((KT) + 2 - 16) * 32, dA_ + 2048 + lbase);                \
      }                                                                       \
      GL16(bS0 + ((KT) + 2) * 32, dB_ + lbase);                               \
      GL16(bS1 + ((KT) + 2) * 32, dB_ + 2048 + lbase);                        \
      GL16(bS2 + ((KT) + 2) * 32, dB_ + 4096 + lbase);                        \
    }                                                                         \
    {                                                                         \
      const ushort_t* Ard_ = lA[(KT) % 3];                                    \
      const ushort_t* Brd_ = lB[(KT) % 3];                                    \
      bf16x8 af[4];                                                           \
      _Pragma("unroll") for (int m = 0; m < 4; ++m)                           \
        af[m] = *(const bf16x8*)(Ard_ + (wr * 64 + m * 16 + frow) * 32 + fswz); \
      _Pragma("unroll") for (int s = 0; s < 3; ++s) {                         \
        bf16x8 b0 = *(const bf16x8*)(Brd_ + s * 2048 +                        \
                                     (wc * 32 + frow) * 32 + fswz);           \
        bf16x8 b1v = *(const bf16x8*)(Brd_ + s * 2048 +                       \
                                      (wc * 32 + 16 + frow) * 32 + fswz);     \
        __builtin_amdgcn_s_setprio(1);                                        \
        _Pragma("unroll") for (int m = 0; m < 4; ++m) {                       \
          acc[s][m][0] = __builtin_amdgcn_mfma_f32_16x16x32_bf16(             \
              af[m], b0, acc[s][m][0], 0, 0, 0);                              \
          acc[s][m][1] = __builtin_amdgcn_mfma_f32_16x16x32_bf16(             \
              af[m], b1v, acc[s][m][1], 0, 0, 0);                             \
        }                                                                     \
        __builtin_amdgcn_s_setprio(0);                                        \
      }                                                                       \
    }                                                                         \
    if constexpr ((KT) + 1 < 32) {                                            \
      if constexpr ((KT) + 2 < 32)                                            \
        asm volatile("s_waitcnt vmcnt(5) lgkmcnt(0)" ::: "memory");           \
      else                                                                    \
        asm volatile("s_waitcnt vmcnt(0) lgkmcnt(0)" ::: "memory");           \
      __builtin_amdgcn_s_barrier();                                           \
    }                                                                         \
  }

__global__ __launch_bounds__(256, 2) void mlp_fused(
    const ushort_t* __restrict__ Pbf,
    const ushort_t* __restrict__ attn,
    const ushort_t* __restrict__ Wt,
    const float* __restrict__ P,
    const float* __restrict__ b1,
    const float* __restrict__ b2,
    const float* __restrict__ b3,
    float* __restrict__ out) {
  __shared__ __align__(16) ushort_t lA[3][4096];     // 128 rows x 32 k
  __shared__ __align__(16) ushort_t lB[3][3 * 2048]; // 3 segs x 64 rows x 32 k
  const int t = threadIdx.x, lane = t & 63, wave = t >> 6;

  // T1: x-fastest chunked XCD swizzle; grid 8 x 128 = 1024 blocks, cpx=128.
  int hblk = blockIdx.x + 8 * blockIdx.y;
  int wk = (hblk & 7) * 128 + (hblk >> 3);
  const int bx = wk & 7;
  const int by = wk >> 3;
  const int bm = by * 128, bn = bx * 64;

  f32x4 acc[3][4][2];
#pragma unroll
  for (int s = 0; s < 3; ++s)
#pragma unroll
    for (int m = 0; m < 4; ++m)
#pragma unroll
      for (int n = 0; n < 2; ++n) acc[s][m][n] = {0.f, 0.f, 0.f, 0.f};

  const int wr = wave >> 1, wc = wave & 1;
  const int frow = lane & 15;
  const int fswz = (((lane >> 4) ^ ((frow >> 1) & 3)) * 8);
  const int srow = t >> 2;
  const int skc = (((t & 3) ^ ((t >> 3) & 3)) * 8);
  const int lbase = (t & 192) * 8;

  const ushort_t* aLo0 = Pbf + (size_t)(bm + srow) * 512 + skc;
  const ushort_t* aLo1 = aLo0 + (size_t)64 * 512;
  const ushort_t* aHi0 = attn + (size_t)(bm + srow) * 512 + skc;
  const ushort_t* aHi1 = aHi0 + (size_t)64 * 512;
  const ushort_t* bS0 = Wt + (size_t)(bn + srow) * 1024 + skc;     // w1^T
  const ushort_t* bS1 = bS0 + (size_t)512 * 1024;                  // w2^T
  const ushort_t* bS2 = bS0 + (size_t)1024 * 1024;                 // w3^T

  // prologue: stage tiles 0 and 1 (5 loads each); wait only for tile 0.
  GL16(aLo0,      lA[0] + lbase);  GL16(aLo1,      lA[0] + 2048 + lbase);
  GL16(bS0,       lB[0] + lbase);  GL16(bS1,       lB[0] + 2048 + lbase);
  GL16(bS2,       lB[0] + 4096 + lbase);
  GL16(aLo0 + 32, lA[1] + lbase);  GL16(aLo1 + 32, lA[1] + 2048 + lbase);
  GL16(bS0 + 32,  lB[1] + lbase);  GL16(bS1 + 32,  lB[1] + 2048 + lbase);
  GL16(bS2 + 32,  lB[1] + 4096 + lbase);
  asm volatile("s_waitcnt vmcnt(5)" ::: "memory");
  __builtin_amdgcn_s_barrier();

  MSTEP(0)  MSTEP(1)  MSTEP(2)  MSTEP(3)  MSTEP(4)  MSTEP(5)  MSTEP(6)  MSTEP(7)
  MSTEP(8)  MSTEP(9)  MSTEP(10) MSTEP(11) MSTEP(12) MSTEP(13) MSTEP(14) MSTEP(15)
  MSTEP(16) MSTEP(17) MSTEP(18) MSTEP(19) MSTEP(20) MSTEP(21) MSTEP(22) MSTEP(23)
  MSTEP(24) MSTEP(25) MSTEP(26) MSTEP(27) MSTEP(28) MSTEP(29) MSTEP(30) MSTEP(31)

  // epilogue: z = tanh(acc0+b1), r = sig(acc1+b2), f = sig(acc2+b3);
  // out = r*P + f*z.  D layout col = lane&15, row = (lane>>4)*4 + i.
#pragma unroll
  for (int m = 0; m < 4; ++m) {
    int row0 = bm + wr * 64 + m * 16 + (lane >> 4) * 4;
#pragma unroll
    for (int n = 0; n < 2; ++n) {
      int col = bn + wc * 32 + n * 16 + frow;
      float B1 = b1[col], B2 = b2[col], B3 = b3[col];
#pragma unroll
      for (int i = 0; i < 4; ++i) {
        size_t idx = (size_t)(row0 + i) * 512 + col;
        float z = tanhf(acc[0][m][n][i] + B1);
        float r = 1.f / (1.f + __expf(-(acc[1][m][n][i] + B2)));
        float f = 1.f / (1.f + __expf(-(acc[2][m][n][i] + B3)));
        out[idx] = r * P[idx] + f * z;
      }
    }
  }
}

// ---------------------------------------------------------------------------
// softmax: in-place row softmax over 1024 bf16 scores, one block per row
__global__ __launch_bounds__(256) void softmax_rows(unsigned short* __restrict__ Sb) {
  __shared__ float red[8];
  unsigned short* p = Sb + (size_t)blockIdx.x * S_LEN;
  int t = threadIdx.x, wave = t >> 6, lane = t & 63;
  ushort4 u = *(ushort4*)(p + t * 4);
  float v0 = bf2f(u.x), v1 = bf2f(u.y), v2 = bf2f(u.z), v3 = bf2f(u.w);
  float mx = fmaxf(fmaxf(v0, v1), fmaxf(v2, v3));
#pragma unroll
  for (int o = 32; o; o >>= 1) mx = fmaxf(mx, __shfl_xor(mx, o));
  if (lane == 0) red[wave] = mx;
  __syncthreads();
  mx = fmaxf(fmaxf(red[0], red[1]), fmaxf(red[2], red[3]));
  float e0 = __expf(v0 - mx), e1 = __expf(v1 - mx);
  float e2 = __expf(v2 - mx), e3 = __expf(v3 - mx);
  float ss = e0 + e1 + e2 + e3;
#pragma unroll
  for (int o = 32; o; o >>= 1) ss += __shfl_xor(ss, o);
  if (lane == 0) red[4 + wave] = ss;
  __syncthreads();
  float inv = 1.f / (red[4] + red[5] + red[6] + red[7]);
  u.x = f2bf(e0 * inv); u.y = f2bf(e1 * inv);
  u.z = f2bf(e2 * inv); u.w = f2bf(e3 * inv);
  *(ushort4*)(p + t * 4) = u;
}

// ---------------------------------------------------------------------------
extern "C" void kernel_launch(void* const* d_in, const int* in_sizes, int n_in,
                              void* d_out, int out_size, void* d_ws, size_t ws_size,
                              hipStream_t stream) {
  const float* P  = (const float*)d_in[0];
  const float* wa = (const float*)d_in[1];
  const float* w1 = (const float*)d_in[2];
  const float* w2 = (const float*)d_in[3];
  const float* w3 = (const float*)d_in[4];
  const float* b1 = (const float*)d_in[5];
  const float* b2 = (const float*)d_in[6];
  const float* b3 = (const float*)d_in[7];
  float* out = (float*)d_out;
  char* ws = (char*)d_ws;
  const size_t MB = 1024 * 1024;

  unsigned short* Pbf  = (unsigned short*)(ws + 0);        // 16 MB
  unsigned short* PT   = (unsigned short*)(ws + 16 * MB);  // 16 MB
  unsigned short* Qbf  = (unsigned short*)(ws + 32 * MB);  // 16 MB
  unsigned short* Sbuf = (unsigned short*)(ws + 48 * MB);  // 32 MB
  unsigned short* attn = (unsigned short*)(ws + 80 * MB);  // 16 MB
  unsigned short* Wt   = (unsigned short*)(ws + 96 * MB);  // 3 MB [1536][1024]
  float*          sj   = (float*)(ws + 99 * MB);           // 64 KB

  const long SD = (long)S_LEN * DDIM;
  const long SS = (long)S_LEN * S_LEN;

  prep_rows<<<4096, 256, 0, stream>>>(P, wa, Pbf, Qbf, sj);
  transpose_b2b<<<dim3(8, 16, NBATCH), 256, 0, stream>>>(Pbf, PT, S_LEN, DDIM, SD, SD);
  transpose_w3<<<dim3(8, 16, 3), 256, 0, stream>>>(w1, w2, w3, Wt);

  // scores: S[b] = Qbf[b] @ Pbf[b]^T + sj[b][col]  (M=N=1024, K=512) — 1024 blocks
  gemm_tb<16, 1><<<dim3(8, 8, NBATCH), 256, 0, stream>>>(
      Qbf, Pbf, Sbuf, sj, 1024, 512, 512, SD, SD, SS, S_LEN);
  softmax_rows<<<16384, 256, 0, stream>>>(Sbuf);
  // attn[b] = SA[b] @ PT[b]^T  (M=1024, N=512, K=1024) — 512 blocks
  gemm_tb<32, 0><<<dim3(4, 8, NBATCH), 256, 0, stream>>>(
      Sbuf, PT, attn, nullptr, 512, 1024, 1024, SS, SD, SD, 0);
  // fused MLP + gate combine
  mlp_fused<<<dim3(8, 128), 256, 0, stream>>>(
      Pbf, attn, Wt, P, b1, b2, b3, out);
}